// Round 5
// baseline (229.347 us; speedup 1.0000x reference)
//
#include <hip/hip_runtime.h>
#include <math.h>

#define NB   8
#define NH   32
#define LQ   4
#define LK   4096
#define DD   128
#define SCALE_F 0.08838834764831845f

// 256 blocks (one per (b,h)), 1024 threads = 16 waves, 1 block/CU.
// THREE-PHASE structure so each block presents ONE pure sequential DRAM
// stream at a time:
//   phase 1: stream K (2 MB sequential) -> raw scores into LDS (64 KB)
//   phase 2: block-wide softmax (global max + exp + sum) over LDS scores
//   phase 3: stream V (2 MB sequential) -> o += w * v, weights broadcast
//            from LDS; no online-rescale chains at all.
// Key->wave mapping stays interleaved (round-4 win): at step s the 16 waves
// cover 64 CONSECUTIVE rows; each wave-level float4 load is 1 KB contiguous.
__global__ __launch_bounds__(1024, 4)
void attn_decode_kernel(const float* __restrict__ Q, const float* __restrict__ K,
                        const float* __restrict__ V, const float* __restrict__ Msk,
                        float* __restrict__ Out)
{
    __shared__ float scores[LQ][LK];      // 64 KB; aliased as o_buf after phase 3
    __shared__ float red_max[LQ][4];
    __shared__ float red_sum[LQ][4];
    __shared__ float g_l[LQ];

    const int bh   = blockIdx.x;          // 0..255
    const int b    = bh >> 5;             // H = 32
    const int tid  = threadIdx.x;
    const int wave = tid >> 6;            // 0..15
    const int lane = tid & 63;
    const int half = lane >> 5;           // 0/1 : which key of the pair
    const int sub  = lane & 31;           // 0..31 : which float4 of the row

    const float* qp = Q   + (size_t)bh * (LQ * DD);
    const float* kp = K   + (size_t)bh * (LK * DD);
    const float* vp = V   + (size_t)bh * (LK * DD);
    const float* mp = Msk + (size_t)b  * (LQ * LK);

    // Q fragments: lane holds q[qi][sub*4 .. sub*4+3]
    float4 q4[LQ];
#pragma unroll
    for (int qi = 0; qi < LQ; ++qi)
        q4[qi] = *(const float4*)(qp + qi * DD + sub * 4);

    // ---------------- phase 1: K stream -> raw scores in LDS ----------------
    for (int s = 0; s < 64; ++s) {
        const int base = s * 64 + wave * 4;   // wave's 4 consecutive rows
        const int ja = base + half;           // half 0 -> row, half 1 -> row+1
        const int jb = ja + 2;

        const float4 ka = *(const float4*)(kp + (size_t)ja * DD + sub * 4);
        const float4 kb = *(const float4*)(kp + (size_t)jb * DD + sub * 4);

        float sa[LQ], sb[LQ];
#pragma unroll
        for (int qi = 0; qi < LQ; ++qi) {
            sa[qi] = ka.x*q4[qi].x + ka.y*q4[qi].y + ka.z*q4[qi].z + ka.w*q4[qi].w;
            sb[qi] = kb.x*q4[qi].x + kb.y*q4[qi].y + kb.z*q4[qi].z + kb.w*q4[qi].w;
        }
#pragma unroll
        for (int msk = 1; msk <= 16; msk <<= 1) {
#pragma unroll
            for (int qi = 0; qi < LQ; ++qi) {
                sa[qi] += __shfl_xor(sa[qi], msk, 64);
                sb[qi] += __shfl_xor(sb[qi], msk, 64);
            }
        }
        if (sub == 0) {                        // lanes 0 and 32 store
#pragma unroll
            for (int qi = 0; qi < LQ; ++qi) {
                scores[qi][ja] = sa[qi] * SCALE_F + mp[qi * LK + ja];
                scores[qi][jb] = sb[qi] * SCALE_F + mp[qi * LK + jb];
            }
        }
    }
    __syncthreads();

    // ---------------- phase 2: block-wide softmax over LDS ----------------
    {
        const int g  = tid >> 8;              // qi group (wave-aligned, 4 waves)
        const int r  = tid & 255;             // rank in group
        const int wg = (tid >> 6) & 3;        // wave index within group

        float lm = -INFINITY;
#pragma unroll
        for (int k = 0; k < 16; ++k)
            lm = fmaxf(lm, scores[g][r + k * 256]);
#pragma unroll
        for (int msk = 1; msk <= 32; msk <<= 1)
            lm = fmaxf(lm, __shfl_xor(lm, msk, 64));
        if (lane == 0) red_max[g][wg] = lm;
        __syncthreads();

        const float m = fmaxf(fmaxf(red_max[g][0], red_max[g][1]),
                              fmaxf(red_max[g][2], red_max[g][3]));
        float ls = 0.0f;
#pragma unroll
        for (int k = 0; k < 16; ++k) {
            const float w = __expf(scores[g][r + k * 256] - m);
            scores[g][r + k * 256] = w;
            ls += w;
        }
#pragma unroll
        for (int msk = 1; msk <= 32; msk <<= 1)
            ls += __shfl_xor(ls, msk, 64);
        if (lane == 0) red_sum[g][wg] = ls;
        __syncthreads();                       // weights + partial sums visible

        if (r == 0)
            g_l[g] = red_sum[g][0] + red_sum[g][1] + red_sum[g][2] + red_sum[g][3];
        // g_l consumed only after the phase-4 syncs below
    }

    // ---------------- phase 3: V stream -> weighted accumulate ----------------
    float4 o4[LQ];
#pragma unroll
    for (int qi = 0; qi < LQ; ++qi) {
        o4[qi].x = 0.0f; o4[qi].y = 0.0f; o4[qi].z = 0.0f; o4[qi].w = 0.0f;
    }

    for (int s = 0; s < 64; ++s) {
        const int base = s * 64 + wave * 4;
        const int ja = base + half;
        const int jb = ja + 2;

        const float4 va = *(const float4*)(vp + (size_t)ja * DD + sub * 4);
        const float4 vb = *(const float4*)(vp + (size_t)jb * DD + sub * 4);

        float wa[LQ], wb[LQ];
#pragma unroll
        for (int qi = 0; qi < LQ; ++qi) {      // LDS broadcast reads (2 addrs)
            wa[qi] = scores[qi][ja];
            wb[qi] = scores[qi][jb];
        }
#pragma unroll
        for (int qi = 0; qi < LQ; ++qi) {
            o4[qi].x += wa[qi] * va.x + wb[qi] * vb.x;
            o4[qi].y += wa[qi] * va.y + wb[qi] * vb.y;
            o4[qi].z += wa[qi] * va.z + wb[qi] * vb.z;
            o4[qi].w += wa[qi] * va.w + wb[qi] * vb.w;
        }
    }

    // combine the two half-wave streams (plain sums now)
#pragma unroll
    for (int qi = 0; qi < LQ; ++qi) {
        o4[qi].x += __shfl_xor(o4[qi].x, 32, 64);
        o4[qi].y += __shfl_xor(o4[qi].y, 32, 64);
        o4[qi].z += __shfl_xor(o4[qi].z, 32, 64);
        o4[qi].w += __shfl_xor(o4[qi].w, 32, 64);
    }

    __syncthreads();                           // scores dead -> reuse as o_buf
    float* ob = &scores[0][0];                 // [16][LQ][DD] = 32 KB alias

    if (half == 0) {
#pragma unroll
        for (int qi = 0; qi < LQ; ++qi)
            *(float4*)&ob[(wave * LQ + qi) * DD + sub * 4] = o4[qi];
    }
    __syncthreads();

    // final cross-wave sum: 512 threads, one (qi, d) each
    if (tid < LQ * DD) {
        const int qi = tid >> 7;
        const int d  = tid & 127;
        float Osum = 0.0f;
#pragma unroll
        for (int w = 0; w < 16; ++w)
            Osum += ob[(w * LQ + qi) * DD + d];
        Out[(size_t)bh * (LQ * DD) + tid] = Osum / g_l[qi];
    }
}

extern "C" void kernel_launch(void* const* d_in, const int* in_sizes, int n_in,
                              void* d_out, int out_size, void* d_ws, size_t ws_size,
                              hipStream_t stream)
{
    const float* q   = (const float*)d_in[0];
    const float* k   = (const float*)d_in[1];
    const float* v   = (const float*)d_in[2];
    const float* msk = (const float*)d_in[3];
    float* out = (float*)d_out;

    attn_decode_kernel<<<dim3(NB * NH), dim3(1024), 0, stream>>>(q, k, v, msk, out);
}

// Round 6
// 208.943 us; speedup vs baseline: 1.0977x; 1.0977x over previous
//
#include <hip/hip_runtime.h>
#include <math.h>

#define NB   8
#define NH   32
#define LQ   4
#define LK   4096
#define DD   128
#define SCALE_F 0.08838834764831845f

// 256 blocks (one per (b,h)), 1024 threads = 16 waves, 1 block/CU.
// Interleaved mapping (round-4 win): at step s the 16 waves cover 128
// CONSECUTIVE key rows (wave w -> rows s*128 + 8w .. 8w+7), so the block's
// in-flight window is one contiguous 64 KB span per array.
// WIDE iteration (round-6 lever): each half-wave processes 4 keys per
// iteration -> 8 KB/wave/iter through ONE 5-step shuffle-reduce chain,
// doubling bytes-per-serial-chain vs round 4.
__global__ __launch_bounds__(1024, 4)
void attn_decode_kernel(const float* __restrict__ Q, const float* __restrict__ K,
                        const float* __restrict__ V, const float* __restrict__ Msk,
                        float* __restrict__ Out)
{
    __shared__ float o_buf[16][LQ][DD];   // 32 KB: per-wave partial outputs
    __shared__ float ml_buf[16][LQ][2];   // per-wave running (m, l)

    const int bh   = blockIdx.x;          // 0..255
    const int b    = bh >> 5;             // H = 32
    const int tid  = threadIdx.x;
    const int wave = tid >> 6;            // 0..15
    const int lane = tid & 63;
    const int half = lane >> 5;           // 0/1
    const int sub  = lane & 31;           // 0..31 : which float4 of the row

    const float* qp = Q   + (size_t)bh * (LQ * DD);
    const float* kp = K   + (size_t)bh * (LK * DD);
    const float* vp = V   + (size_t)bh * (LK * DD);
    const float* mp = Msk + (size_t)b  * (LQ * LK);

    // Q fragments: lane holds q[qi][sub*4 .. sub*4+3]
    float4 q4[LQ];
#pragma unroll
    for (int qi = 0; qi < LQ; ++qi)
        q4[qi] = *(const float4*)(qp + qi * DD + sub * 4);

    float m_run[LQ], l_run[LQ];
    float4 o4[LQ];
#pragma unroll
    for (int qi = 0; qi < LQ; ++qi) {
        m_run[qi] = -INFINITY;
        l_run[qi] = 0.0f;
        o4[qi].x = 0.0f; o4[qi].y = 0.0f; o4[qi].z = 0.0f; o4[qi].w = 0.0f;
    }

    for (int s = 0; s < 32; ++s) {
        // this wave's 8 consecutive rows; this half's 4 keys: +0,+2,+4,+6
        const int base = s * 128 + wave * 8 + half;
        const float* krow = kp + (size_t)base * DD + sub * 4;
        const float* vrow = vp + (size_t)base * DD + sub * 4;

        // issue all 8 loads up front (8 KB / wave / iteration)
        const float4 k0 = *(const float4*)(krow);
        const float4 k1 = *(const float4*)(krow + 2 * DD);
        const float4 k2 = *(const float4*)(krow + 4 * DD);
        const float4 k3 = *(const float4*)(krow + 6 * DD);
        const float4 v0 = *(const float4*)(vrow);
        const float4 v1 = *(const float4*)(vrow + 2 * DD);
        const float4 v2 = *(const float4*)(vrow + 4 * DD);
        const float4 v3 = *(const float4*)(vrow + 6 * DD);

        // per-lane partial dots: 4 keys x 4 queries
        float s0[LQ], s1[LQ], s2[LQ], s3[LQ];
#pragma unroll
        for (int qi = 0; qi < LQ; ++qi) {
            s0[qi] = k0.x*q4[qi].x + k0.y*q4[qi].y + k0.z*q4[qi].z + k0.w*q4[qi].w;
            s1[qi] = k1.x*q4[qi].x + k1.y*q4[qi].y + k1.z*q4[qi].z + k1.w*q4[qi].w;
            s2[qi] = k2.x*q4[qi].x + k2.y*q4[qi].y + k2.z*q4[qi].z + k2.w*q4[qi].w;
            s3[qi] = k3.x*q4[qi].x + k3.y*q4[qi].y + k3.z*q4[qi].z + k3.w*q4[qi].w;
        }

        // ONE 5-step reduce chain covers all 16 partials
#pragma unroll
        for (int msk = 1; msk <= 16; msk <<= 1) {
#pragma unroll
            for (int qi = 0; qi < LQ; ++qi) {
                s0[qi] += __shfl_xor(s0[qi], msk, 64);
                s1[qi] += __shfl_xor(s1[qi], msk, 64);
                s2[qi] += __shfl_xor(s2[qi], msk, 64);
                s3[qi] += __shfl_xor(s3[qi], msk, 64);
            }
        }

        // online softmax: one rescale per 4 keys
#pragma unroll
        for (int qi = 0; qi < LQ; ++qi) {
            const float sv0 = s0[qi] * SCALE_F + mp[qi * LK + base];
            const float sv1 = s1[qi] * SCALE_F + mp[qi * LK + base + 2];
            const float sv2 = s2[qi] * SCALE_F + mp[qi * LK + base + 4];
            const float sv3 = s3[qi] * SCALE_F + mp[qi * LK + base + 6];
            const float mn  = fmaxf(fmaxf(m_run[qi], fmaxf(sv0, sv1)),
                                    fmaxf(sv2, sv3));
            const float f  = __expf(m_run[qi] - mn);
            const float p0 = __expf(sv0 - mn);
            const float p1 = __expf(sv1 - mn);
            const float p2 = __expf(sv2 - mn);
            const float p3 = __expf(sv3 - mn);
            m_run[qi] = mn;
            l_run[qi] = l_run[qi] * f + ((p0 + p1) + (p2 + p3));
            o4[qi].x = o4[qi].x * f + p0*v0.x + p1*v1.x + p2*v2.x + p3*v3.x;
            o4[qi].y = o4[qi].y * f + p0*v0.y + p1*v1.y + p2*v2.y + p3*v3.y;
            o4[qi].z = o4[qi].z * f + p0*v0.z + p1*v1.z + p2*v2.z + p3*v3.z;
            o4[qi].w = o4[qi].w * f + p0*v0.w + p1*v1.w + p2*v2.w + p3*v3.w;
        }
    }

    // combine the two half-wave streams in-register (lanes l and l^32)
#pragma unroll
    for (int qi = 0; qi < LQ; ++qi) {
        const float m_o = __shfl_xor(m_run[qi], 32, 64);
        const float l_o = __shfl_xor(l_run[qi], 32, 64);
        float4 oo;
        oo.x = __shfl_xor(o4[qi].x, 32, 64);
        oo.y = __shfl_xor(o4[qi].y, 32, 64);
        oo.z = __shfl_xor(o4[qi].z, 32, 64);
        oo.w = __shfl_xor(o4[qi].w, 32, 64);
        const float M  = fmaxf(m_run[qi], m_o);
        const float fo = __expf(m_run[qi] - M);
        const float fx = __expf(m_o - M);
        o4[qi].x = o4[qi].x * fo + oo.x * fx;
        o4[qi].y = o4[qi].y * fo + oo.y * fx;
        o4[qi].z = o4[qi].z * fo + oo.z * fx;
        o4[qi].w = o4[qi].w * fo + oo.w * fx;
        l_run[qi] = l_run[qi] * fo + l_o * fx;
        m_run[qi] = M;
    }

    // stage per-wave partials to LDS
    if (half == 0) {
#pragma unroll
        for (int qi = 0; qi < LQ; ++qi)
            *(float4*)&o_buf[wave][qi][sub * 4] = o4[qi];
        if (sub == 0) {
#pragma unroll
            for (int qi = 0; qi < LQ; ++qi) {
                ml_buf[wave][qi][0] = m_run[qi];
                ml_buf[wave][qi][1] = l_run[qi];
            }
        }
    }
    __syncthreads();

    // final cross-wave combine: 512 threads, one (qi, d) each
    if (tid < LQ * DD) {
        const int qi = tid >> 7;
        const int d  = tid & 127;
        float M = -INFINITY;
#pragma unroll
        for (int w = 0; w < 16; ++w)
            M = fmaxf(M, ml_buf[w][qi][0]);
        float Lsum = 0.0f, Osum = 0.0f;
#pragma unroll
        for (int w = 0; w < 16; ++w) {
            const float f = __expf(ml_buf[w][qi][0] - M);
            Lsum += ml_buf[w][qi][1] * f;
            Osum += o_buf[w][qi][d] * f;
        }
        Out[(size_t)bh * (LQ * DD) + tid] = Osum / Lsum;
    }
}

extern "C" void kernel_launch(void* const* d_in, const int* in_sizes, int n_in,
                              void* d_out, int out_size, void* d_ws, size_t ws_size,
                              hipStream_t stream)
{
    const float* q   = (const float*)d_in[0];
    const float* k   = (const float*)d_in[1];
    const float* v   = (const float*)d_in[2];
    const float* msk = (const float*)d_in[3];
    float* out = (float*)d_out;

    attn_decode_kernel<<<dim3(NB * NH), dim3(1024), 0, stream>>>(q, k, v, msk, out);
}

// Round 8
// 170.811 us; speedup vs baseline: 1.3427x; 1.2232x over previous
//
#include <hip/hip_runtime.h>
#include <math.h>

#define NB   8
#define NH   32
#define LQ   4
#define LK   4096
#define DD   128
#define SCALE_F 0.08838834764831845f

typedef float f32x4 __attribute__((ext_vector_type(4)));  // native clang vector
                                                          // (nontemporal-builtin OK)

// Round-4 winner (188.7 us, 5.69 TB/s) + NON-TEMPORAL K/V loads.
// 256 blocks (one per (b,h)), 1024 threads = 16 waves, 1 block/CU.
// Interleaved key mapping: at step s the 16 waves cover 64 CONSECUTIVE rows
// (wave w -> rows s*64 + 4w .. 4w+3) -> block window is one contiguous 32 KB
// span per array. Each wave-level float4 load is 1 KB contiguous.
// K/V are streamed once with zero reuse -> nt loads skip cache retention.
__global__ __launch_bounds__(1024, 4)
void attn_decode_kernel(const float* __restrict__ Q, const float* __restrict__ K,
                        const float* __restrict__ V, const float* __restrict__ Msk,
                        float* __restrict__ Out)
{
    __shared__ float o_buf[16][LQ][DD];   // 32 KB: per-wave partial outputs
    __shared__ float ml_buf[16][LQ][2];   // per-wave running (m, l)

    const int bh   = blockIdx.x;          // 0..255
    const int b    = bh >> 5;             // H = 32
    const int tid  = threadIdx.x;
    const int wave = tid >> 6;            // 0..15
    const int lane = tid & 63;
    const int half = lane >> 5;           // 0/1 : which key of the pair
    const int sub  = lane & 31;           // 0..31 : which float4 of the row

    const float* qp = Q   + (size_t)bh * (LQ * DD);
    const float* kp = K   + (size_t)bh * (LK * DD);
    const float* vp = V   + (size_t)bh * (LK * DD);
    const float* mp = Msk + (size_t)b  * (LQ * LK);

    // Q fragments: lane holds q[qi][sub*4 .. sub*4+3]
    f32x4 q4[LQ];
#pragma unroll
    for (int qi = 0; qi < LQ; ++qi)
        q4[qi] = *(const f32x4*)(qp + qi * DD + sub * 4);

    float m_run[LQ], l_run[LQ];
    f32x4 o4[LQ];
#pragma unroll
    for (int qi = 0; qi < LQ; ++qi) {
        m_run[qi] = -INFINITY;
        l_run[qi] = 0.0f;
        o4[qi] = (f32x4)0.0f;
    }

    for (int s = 0; s < 64; ++s) {
        const int base = s * 64 + wave * 4;   // this wave's 4 consecutive rows
        const int ja = base + half;           // half 0 -> row, half 1 -> row+1
        const int jb = ja + 2;

        // issue all 4 vector loads up front (4 KB / wave / iteration total)
        const f32x4 ka = __builtin_nontemporal_load((const f32x4*)(kp + (size_t)ja * DD + sub * 4));
        const f32x4 kb = __builtin_nontemporal_load((const f32x4*)(kp + (size_t)jb * DD + sub * 4));
        const f32x4 va = __builtin_nontemporal_load((const f32x4*)(vp + (size_t)ja * DD + sub * 4));
        const f32x4 vb = __builtin_nontemporal_load((const f32x4*)(vp + (size_t)jb * DD + sub * 4));

        // per-lane partial dot products
        float sa[LQ], sb[LQ];
#pragma unroll
        for (int qi = 0; qi < LQ; ++qi) {
            sa[qi] = ka.x*q4[qi].x + ka.y*q4[qi].y + ka.z*q4[qi].z + ka.w*q4[qi].w;
            sb[qi] = kb.x*q4[qi].x + kb.y*q4[qi].y + kb.z*q4[qi].z + kb.w*q4[qi].w;
        }
        // reduce across the 32-lane half (xor masks < 32 stay inside the half)
#pragma unroll
        for (int msk = 1; msk <= 16; msk <<= 1) {
#pragma unroll
            for (int qi = 0; qi < LQ; ++qi) {
                sa[qi] += __shfl_xor(sa[qi], msk, 64);
                sb[qi] += __shfl_xor(sb[qi], msk, 64);
            }
        }

        // online softmax update: one rescale per 2 keys
#pragma unroll
        for (int qi = 0; qi < LQ; ++qi) {
            const float s_a = sa[qi] * SCALE_F + mp[qi * LK + ja];
            const float s_b = sb[qi] * SCALE_F + mp[qi * LK + jb];
            const float mn  = fmaxf(m_run[qi], fmaxf(s_a, s_b));   // v_max3
            const float f   = __expf(m_run[qi] - mn);
            const float pa  = __expf(s_a - mn);
            const float pb  = __expf(s_b - mn);
            m_run[qi] = mn;
            l_run[qi] = l_run[qi] * f + pa + pb;
            o4[qi].x = o4[qi].x * f + pa * va.x + pb * vb.x;
            o4[qi].y = o4[qi].y * f + pa * va.y + pb * vb.y;
            o4[qi].z = o4[qi].z * f + pa * va.z + pb * vb.z;
            o4[qi].w = o4[qi].w * f + pa * va.w + pb * vb.w;
        }
    }

    // combine the two half-wave streams in-register (same dims, lanes l and l^32)
#pragma unroll
    for (int qi = 0; qi < LQ; ++qi) {
        const float m_o = __shfl_xor(m_run[qi], 32, 64);
        const float l_o = __shfl_xor(l_run[qi], 32, 64);
        f32x4 oo;
        oo.x = __shfl_xor(o4[qi].x, 32, 64);
        oo.y = __shfl_xor(o4[qi].y, 32, 64);
        oo.z = __shfl_xor(o4[qi].z, 32, 64);
        oo.w = __shfl_xor(o4[qi].w, 32, 64);
        const float M  = fmaxf(m_run[qi], m_o);
        const float fo = __expf(m_run[qi] - M);
        const float fx = __expf(m_o - M);
        o4[qi].x = o4[qi].x * fo + oo.x * fx;
        o4[qi].y = o4[qi].y * fo + oo.y * fx;
        o4[qi].z = o4[qi].z * fo + oo.z * fx;
        o4[qi].w = o4[qi].w * fo + oo.w * fx;
        l_run[qi] = l_run[qi] * fo + l_o * fx;
        m_run[qi] = M;
    }

    // stage per-wave partials to LDS
    if (half == 0) {
#pragma unroll
        for (int qi = 0; qi < LQ; ++qi)
            *(f32x4*)&o_buf[wave][qi][sub * 4] = o4[qi];
        if (sub == 0) {
#pragma unroll
            for (int qi = 0; qi < LQ; ++qi) {
                ml_buf[wave][qi][0] = m_run[qi];
                ml_buf[wave][qi][1] = l_run[qi];
            }
        }
    }
    __syncthreads();

    // final cross-wave combine: 512 threads, one (qi, d) each
    if (tid < LQ * DD) {
        const int qi = tid >> 7;
        const int d  = tid & 127;
        float M = -INFINITY;
#pragma unroll
        for (int w = 0; w < 16; ++w)
            M = fmaxf(M, ml_buf[w][qi][0]);
        float Lsum = 0.0f, Osum = 0.0f;
#pragma unroll
        for (int w = 0; w < 16; ++w) {
            const float f = __expf(ml_buf[w][qi][0] - M);
            Lsum += ml_buf[w][qi][1] * f;
            Osum += o_buf[w][qi][d] * f;
        }
        Out[(size_t)bh * (LQ * DD) + tid] = Osum / Lsum;
    }
}

extern "C" void kernel_launch(void* const* d_in, const int* in_sizes, int n_in,
                              void* d_out, int out_size, void* d_ws, size_t ws_size,
                              hipStream_t stream)
{
    const float* q   = (const float*)d_in[0];
    const float* k   = (const float*)d_in[1];
    const float* v   = (const float*)d_in[2];
    const float* msk = (const float*)d_in[3];
    float* out = (float*)d_out;

    attn_decode_kernel<<<dim3(NB * NH), dim3(1024), 0, stream>>>(q, k, v, msk, out);
}